// Round 9
// baseline (335.245 us; speedup 1.0000x reference)
//
#include <hip/hip_runtime.h>
#include <hip/hip_bf16.h>
#include <stdint.h>

#define S_LEN 4096
#define EMB   1024
#define NH    8
#define HD    128

typedef __bf16 bf16x8 __attribute__((ext_vector_type(8)));
typedef float  f32x4  __attribute__((ext_vector_type(4)));
typedef short  s16x4  __attribute__((ext_vector_type(4)));

__device__ __forceinline__ unsigned short f2bf(float f) {
  unsigned int u = __float_as_uint(f);
  u += 0x7fffu + ((u >> 16) & 1u);
  return (unsigned short)(u >> 16);
}
__device__ __forceinline__ float bf2f(unsigned short u) {
  return __uint_as_float(((unsigned int)u) << 16);
}

typedef __attribute__((address_space(3))) void lds_void_t;
typedef const __attribute__((address_space(1))) void gbl_void_t;

__device__ __forceinline__ void load_lds16(const void* g, void* l) {
  __builtin_amdgcn_global_load_lds((gbl_void_t*)g, (lds_void_t*)l, 16, 0, 0);
}

// ---------------- weight transpose+convert ----------------
// wT layout: [0,1M)=wq^T, [1M,2M)=wv^T  (the 2048-wide QV GEMM B);  [2M,3M)=wk^T (kexact)
__global__ __launch_bounds__(256) void conv_w(const float* wq, const float* wk, const float* wv,
                                              const float* wo, unsigned short* wT, unsigned short* woT,
                                              unsigned short* wkm) {
  int z = blockIdx.z;
  const float* src = (z == 0) ? wq : (z == 1) ? wk : (z == 2) ? wv : wo;
  unsigned short* dst = (z == 0) ? wT
                      : (z == 2) ? wT + (size_t)1 * 1024 * 1024
                      : (z == 1) ? wT + (size_t)2 * 1024 * 1024
                                 : woT;
  __shared__ float tl[32][33];
  int tx = threadIdx.x & 31, ty = threadIdx.x >> 5;
  int c0 = blockIdx.x * 32, r0 = blockIdx.y * 32;
#pragma unroll
  for (int i = 0; i < 4; ++i)
    tl[ty + 8 * i][tx] = src[(size_t)(r0 + ty + 8 * i) * 1024 + c0 + tx];
  __syncthreads();
#pragma unroll
  for (int i = 0; i < 4; ++i) {
    float v = tl[tx][ty + 8 * i];
    unsigned short h = f2bf(v);
    size_t o = (size_t)(c0 + ty + 8 * i) * 1024 + r0 + tx;
    dst[o] = h;
    if (z == 1) wkm[o] = f2bf(v - bf2f(h));
  }
}

// ---------------- x convert (2-plane split) + rep-row gather ----------------
__global__ __launch_bounds__(256) void conv_x(const float* x, unsigned short* xh, unsigned short* xm,
                                              float* xrep) {
  int idx = blockIdx.x * 256 + threadIdx.x;
  if (idx < 4194304) {
    float v = x[idx];
    unsigned short h = f2bf(v);
    xh[idx] = h;
    xm[idx] = f2bf(v - bf2f(h));
  }
  if (idx < 32768) {
    int r = idx >> 10, e = idx & 1023;
    xrep[idx] = x[(size_t)(r * 128 + 127) * 1024 + e];
  }
}

// ---------------- fused QV-GEMM + exact-K GEMM (blockIdx-parity dispatch) ----------------
// Even blocks: C_qv[M=4096,N=2048] = x_bf * [wq|wv]^T (bf16 out).  Odd blocks: exact K via
// 2-plane split MFMA (hh+hm+mh+mm) + fused RoPE epilogue -> kf32 + k_bf.  Interleaved so
// each CU co-hosts ~2 QV + ~2 kexact blocks: one kernel's barrier-drain stalls are filled
// by the other's MFMA/staging (m114 wave-level overlap; multi-stream is banned by capture).
__global__ __launch_bounds__(256) void qv_kexact(const unsigned short* Ah, const unsigned short* Am,
                                                 const unsigned short* wqv, const unsigned short* Bh,
                                                 const unsigned short* Bm, const float* cosb,
                                                 const float* sinb, unsigned short* qv_bf,
                                                 float* C, unsigned short* k_bf) {
  __shared__ unsigned short lds[12288];  // 24KB union: QV {Asm 8KB|Bsm 8KB} / kexact {As 8KB|Bs 16KB}
  int tid = threadIdx.x;
  int w = tid >> 6, l = tid & 63, quad = l >> 4, l16 = l & 15;
  int wm = w >> 1, wn = w & 1;
  int sl = (quad ^ ((l16 >> 1) & 3)) * 8;
  f32x4 z4 = {0.f, 0.f, 0.f, 0.f};
  if ((blockIdx.x & 1) == 0) {
    // ---- QV GEMM: 128x128 tile, N=2048 ----
    int bid = blockIdx.x >> 1;
    int m0 = (bid >> 4) * 128, n0 = (bid & 15) * 128;
    unsigned short* Asm = lds;
    unsigned short* Bsm = lds + 4096;
    f32x4 acc[4][4];
#pragma unroll
    for (int i = 0; i < 4; ++i)
#pragma unroll
      for (int j = 0; j < 4; ++j) acc[i][j] = z4;
    const unsigned short* Ag = Ah + (size_t)m0 * 1024;
    const unsigned short* Bg = wqv + (size_t)n0 * 1024;
    for (int kt = 0; kt < 1024; kt += 32) {
#pragma unroll
      for (int it = 0; it < 2; ++it) {
        int c = it * 256 + tid;
        int row = c >> 2, sg = c & 3;
        int sw = (sg ^ ((row >> 1) & 3)) * 8;
        load_lds16(Ag + (size_t)row * 1024 + kt + sw, &Asm[(it * 256 + (tid & 192)) * 8]);
        load_lds16(Bg + (size_t)row * 1024 + kt + sw, &Bsm[(it * 256 + (tid & 192)) * 8]);
      }
      __syncthreads();
      bf16x8 af[4], bfr[4];
#pragma unroll
      for (int i = 0; i < 4; ++i) {
        af[i]  = *(const bf16x8*)&Asm[(wm * 64 + i * 16 + l16) * 32 + sl];
        bfr[i] = *(const bf16x8*)&Bsm[(wn * 64 + i * 16 + l16) * 32 + sl];
      }
#pragma unroll
      for (int mi = 0; mi < 4; ++mi)
#pragma unroll
        for (int ni = 0; ni < 4; ++ni)
          acc[mi][ni] = __builtin_amdgcn_mfma_f32_16x16x32_bf16(af[mi], bfr[ni], acc[mi][ni], 0, 0, 0);
      __syncthreads();
    }
#pragma unroll
    for (int mi = 0; mi < 4; ++mi)
#pragma unroll
      for (int ni = 0; ni < 4; ++ni)
#pragma unroll
        for (int r = 0; r < 4; ++r) {
          int row = m0 + wm * 64 + mi * 16 + quad * 4 + r;
          int col = n0 + wn * 64 + ni * 16 + l16;
          qv_bf[(size_t)row * 2048 + col] = f2bf(acc[mi][ni][r]);
        }
  } else {
    // ---- exact K: 64x128 tile, 2-plane split, fused RoPE epilogue ----
    int bid = blockIdx.x >> 1;
    int bx = bid & 7, by = bid >> 3;
    int m0 = by * 64, n0 = bx * 128;
    unsigned short* As = lds;          // 2 planes x 2048
    unsigned short* Bs = lds + 4096;   // 2 planes x 4096
    f32x4 acc[2][4];
#pragma unroll
    for (int i = 0; i < 2; ++i)
#pragma unroll
      for (int j = 0; j < 4; ++j) acc[i][j] = z4;
    const unsigned short* Aps[2] = {Ah + (size_t)m0 * 1024, Am + (size_t)m0 * 1024};
    const unsigned short* Bps[2] = {Bh + (size_t)n0 * 1024, Bm + (size_t)n0 * 1024};
    int arow = tid >> 2, asg = tid & 3;
    int asw = (asg ^ ((arow >> 1) & 3)) * 8;
    for (int kt = 0; kt < 1024; kt += 32) {
#pragma unroll
      for (int p = 0; p < 2; ++p) {
        load_lds16(Aps[p] + (size_t)arow * 1024 + kt + asw, &As[p * 2048 + (tid & 192) * 8]);
#pragma unroll
        for (int it = 0; it < 2; ++it) {
          int c = it * 256 + tid;
          int row = c >> 2, sg = c & 3;
          int sw = (sg ^ ((row >> 1) & 3)) * 8;
          load_lds16(Bps[p] + (size_t)row * 1024 + kt + sw,
                     &Bs[p * 4096 + (it * 256 + (tid & 192)) * 8]);
        }
      }
      __syncthreads();
      bf16x8 af[2][2], bfr[2][4];
#pragma unroll
      for (int p = 0; p < 2; ++p) {
#pragma unroll
        for (int i = 0; i < 2; ++i)
          af[p][i] = *(const bf16x8*)&As[p * 2048 + (wm * 32 + i * 16 + l16) * 32 + sl];
#pragma unroll
        for (int j = 0; j < 4; ++j)
          bfr[p][j] = *(const bf16x8*)&Bs[p * 4096 + (wn * 64 + j * 16 + l16) * 32 + sl];
      }
#pragma unroll
      for (int mi = 0; mi < 2; ++mi)
#pragma unroll
        for (int ni = 0; ni < 4; ++ni) {
          f32x4 a = acc[mi][ni];
          a = __builtin_amdgcn_mfma_f32_16x16x32_bf16(af[0][mi], bfr[0][ni], a, 0, 0, 0); // hh
          a = __builtin_amdgcn_mfma_f32_16x16x32_bf16(af[0][mi], bfr[1][ni], a, 0, 0, 0); // hm
          a = __builtin_amdgcn_mfma_f32_16x16x32_bf16(af[1][mi], bfr[0][ni], a, 0, 0, 0); // mh
          a = __builtin_amdgcn_mfma_f32_16x16x32_bf16(af[1][mi], bfr[1][ni], a, 0, 0, 0); // mm
          acc[mi][ni] = a;
        }
      __syncthreads();
    }
    // -------- fused RoPE epilogue --------
    float* BsF = (float*)Bs;  // 64x64 fp32 = 16KB b-half exchange
    if (wn == 1) {
#pragma unroll
      for (int mi = 0; mi < 2; ++mi)
#pragma unroll
        for (int ni = 0; ni < 4; ++ni)
#pragma unroll
          for (int r = 0; r < 4; ++r)
            BsF[(wm * 32 + mi * 16 + quad * 4 + r) * 64 + ni * 16 + l16] = acc[mi][ni][r];
    }
    __syncthreads();
    if (wn == 0) {
      int h = bx;
#pragma unroll
      for (int mi = 0; mi < 2; ++mi)
#pragma unroll
        for (int ni = 0; ni < 4; ++ni)
#pragma unroll
          for (int r = 0; r < 4; ++r) {
            int rl = wm * 32 + mi * 16 + quad * 4 + r;
            int j  = ni * 16 + l16;
            int s  = m0 + rl;
            float a = acc[mi][ni][r];
            float b = BsF[rl * 64 + j];
            float c = cosb[s * 64 + j], sn = sinb[s * 64 + j];
            float a2 = a * c - b * sn;
            float b2 = b * c + a * sn;
            size_t e = (size_t)s * 1024 + h * 128 + j;
            C[e]      = a2;
            C[e + 64] = b2;
            size_t kb = ((size_t)h * S_LEN + s) * 128 + j;
            k_bf[kb]      = f2bf(a2);
            k_bf[kb + 64] = f2bf(b2);
          }
    }
  }
}

// ---------------- 64x128-tile fp32-out GEMM (2 blocks/CU for the out-projection) ----------------
__global__ __launch_bounds__(256) void gemm_bt64(const unsigned short* A, const unsigned short* B,
                                                 float* C) {
  __shared__ unsigned short As[2048];   // 64x32
  __shared__ unsigned short Bs[4096];   // 128x32
  int tid = threadIdx.x;
  int w = tid >> 6, l = tid & 63, quad = l >> 4, l16 = l & 15;
  int wm = w >> 1, wn = w & 1;
  int m0 = blockIdx.y * 64, n0 = blockIdx.x * 128;
  f32x4 acc[2][4];
  f32x4 z4 = {0.f, 0.f, 0.f, 0.f};
#pragma unroll
  for (int i = 0; i < 2; ++i)
#pragma unroll
    for (int j = 0; j < 4; ++j) acc[i][j] = z4;
  const unsigned short* Ag = A + (size_t)m0 * 1024;
  const unsigned short* Bg = B + (size_t)n0 * 1024;
  int arow = tid >> 2, asg = tid & 3;
  int asw = (asg ^ ((arow >> 1) & 3)) * 8;
  int sl = (quad ^ ((l16 >> 1) & 3)) * 8;
  for (int kt = 0; kt < 1024; kt += 32) {
    load_lds16(Ag + (size_t)arow * 1024 + kt + asw, &As[(tid & 192) * 8]);
#pragma unroll
    for (int it = 0; it < 2; ++it) {
      int c = it * 256 + tid;
      int row = c >> 2, sg = c & 3;
      int sw = (sg ^ ((row >> 1) & 3)) * 8;
      load_lds16(Bg + (size_t)row * 1024 + kt + sw, &Bs[(it * 256 + (tid & 192)) * 8]);
    }
    __syncthreads();
    bf16x8 af[2], bfr[4];
#pragma unroll
    for (int i = 0; i < 2; ++i)
      af[i] = *(const bf16x8*)&As[(wm * 32 + i * 16 + l16) * 32 + sl];
#pragma unroll
    for (int j = 0; j < 4; ++j)
      bfr[j] = *(const bf16x8*)&Bs[(wn * 64 + j * 16 + l16) * 32 + sl];
#pragma unroll
    for (int mi = 0; mi < 2; ++mi)
#pragma unroll
      for (int ni = 0; ni < 4; ++ni)
        acc[mi][ni] = __builtin_amdgcn_mfma_f32_16x16x32_bf16(af[mi], bfr[ni], acc[mi][ni], 0, 0, 0);
    __syncthreads();
  }
#pragma unroll
  for (int mi = 0; mi < 2; ++mi)
#pragma unroll
    for (int ni = 0; ni < 4; ++ni)
#pragma unroll
      for (int r = 0; r < 4; ++r) {
        int row = m0 + wm * 32 + mi * 16 + quad * 4 + r;
        int col = n0 + wn * 64 + ni * 16 + l16;
        C[(size_t)row * 1024 + col] = acc[mi][ni][r];
      }
}

// ---------------- qrep GEMM ----------------
__global__ __launch_bounds__(256) void qrep_gemm(const float* xrep, const float* wq, float* qparts) {
  int n0 = blockIdx.x * 32;
  int p  = blockIdx.y;
  int k0 = p * 128;
  int tid = threadIdx.x;
  __shared__ float xs[32 * 132];
  __shared__ float wsm[128 * 36];
#pragma unroll
  for (int i = 0; i < 4; ++i) {
    int c = tid + 256 * i;
    int m = c >> 5, kc = (c & 31) * 4;
    *(f32x4*)&xs[m * 132 + kc] = *(const f32x4*)&xrep[(size_t)m * 1024 + k0 + kc];
  }
#pragma unroll
  for (int i = 0; i < 4; ++i) {
    int c = tid + 256 * i;
    int k = c >> 3, n = (c & 7) * 4;
    *(f32x4*)&wsm[k * 36 + n] = *(const f32x4*)&wq[(size_t)(k0 + k) * 1024 + n0 + n];
  }
  __syncthreads();
#pragma unroll
  for (int i = 0; i < 4; ++i) {
    int o = tid + 256 * i;
    int m = o >> 5, n = o & 31;
    float acc = 0.f;
#pragma unroll 16
    for (int k = 0; k < 128; ++k) acc += xs[m * 132 + k] * wsm[k * 36 + n];
    qparts[((size_t)p * 32 + m) * 1024 + n0 + n] = acc;
  }
}

__global__ __launch_bounds__(256) void qsum(const float* qparts, float* qrep) {
  int i = blockIdx.x * 256 + threadIdx.x;
  float s = 0.f;
#pragma unroll
  for (int p = 0; p < 8; ++p) s += qparts[(size_t)p * 32768 + i];
  qrep[i] = s;
}

// ---------------- RoPE + pack: q (pre-scaled) + v-transpose from the 2048-wide QV buffer ----------------
__global__ __launch_bounds__(256) void rope_pack(const unsigned short* qv, const float* cosb,
                                                 const float* sinb, unsigned short* q_bf,
                                                 unsigned short* vT) {
  int h = blockIdx.y;
  int s0 = blockIdx.x * 64;
  int tid = threadIdx.x;
  const float sc2 = 0.12751712f;  // (1/sqrt(128)) * log2(e), folded into q
  __shared__ unsigned short vt[128 * 66];
  for (int idx = tid; idx < 4096; idx += 256) {
    int r = idx >> 6, j = idx & 63;
    int s = s0 + r;
    float c = cosb[s * 64 + j], sn = sinb[s * 64 + j];
    const unsigned short* row = qv + (size_t)s * 2048 + h * 128;
    size_t ob = ((size_t)h * S_LEN + s) * 128;
    float a = bf2f(row[j]), b = bf2f(row[j + 64]);
    q_bf[ob + j]      = f2bf((a * c - b * sn) * sc2);
    q_bf[ob + j + 64] = f2bf((b * c + a * sn) * sc2);
  }
  for (int idx = tid; idx < 8192; idx += 256) {
    int r = idx >> 7, d = idx & 127;
    vt[d * 66 + r] = qv[(size_t)(s0 + r) * 2048 + 1024 + h * 128 + d];
  }
  __syncthreads();
  for (int idx = tid; idx < 8192; idx += 256) {
    int d = idx >> 6, c = idx & 63;
    vT[((size_t)h * 128 + d) * S_LEN + s0 + c] = vt[d * 66 + c];
  }
}

// ---------------- flash attention: transposed-S, register P, K-tile 64, 4 blocks/CU ----------------
// Counted-vmcnt pipeline (R6). Per tile: vmcnt(4)+bar [K ready] -> QK -> vmcnt(0)+bar
// [V ready, Ks reads done] -> issue K(j+1) -> softmax -> PV -> bar -> issue V(j+1).
#define STAGE_K(jj)                                                          \
  {                                                                          \
    _Pragma("unroll")                                                        \
    for (int it = 0; it < 4; ++it) {                                         \
      int c = it * 256 + tid;                                                \
      int kc = c >> 8, cc = c & 255, key = cc >> 2, sg = cc & 3;             \
      int sw = (sg ^ ((key >> 1) & 3)) * 8;                                  \
      load_lds16(kbase + (size_t)((jj) * 64 + key) * 128 + kc * 32 + sw,     \
                 &Ks[(it * 256 + (tid & 192)) * 8]);                         \
    }                                                                        \
  }
#define STAGE_V(jj)                                                          \
  {                                                                          \
    _Pragma("unroll")                                                        \
    for (int it = 0; it < 4; ++it) {                                         \
      int c = it * 256 + tid;                                                \
      int kcv = c >> 9, ccv = c & 511, d = ccv >> 2, sgv = c & 3;            \
      int swv = (sgv ^ ((d >> 1) & 3)) * 8;                                  \
      load_lds16(vbase + (size_t)d * S_LEN + (jj) * 64 + kcv * 32 + swv,     \
                 &Vs[(it * 256 + (tid & 192)) * 8]);                         \
    }                                                                        \
  }

__global__ __launch_bounds__(256, 4) void flash_attn(const unsigned short* q_bf,
                                                     const unsigned short* k_bf,
                                                     const unsigned short* vT,
                                                     unsigned short* Opart,
                                                     float* mpart, float* lpart) {
  int h = blockIdx.x;
  int y = blockIdx.y;
  int qt = (y < 32) ? y : 95 - y;
  int split = blockIdx.z;
  int tid = threadIdx.x, w = tid >> 6, l = tid & 63, quad = l >> 4, l16 = l & 15;
  __shared__ unsigned short Ks[8192]; // 16KB: [kc4(dim)][key64][32dims] swizzled
  __shared__ unsigned short Vs[8192]; // 16KB: [kc2(key)][d128][32keys] swizzled
  const unsigned short* qbase = q_bf + (size_t)h * S_LEN * 128;
  const unsigned short* kbase = k_bf + (size_t)h * S_LEN * 128;
  const unsigned short* vbase = vT + (size_t)h * 128 * S_LEN;
  int sl = (quad ^ ((l16 >> 1) & 3)) * 8;
  int qrow = qt * 64 + w * 16 + l16;
  bf16x8 qf[4];
#pragma unroll
  for (int kc = 0; kc < 4; ++kc)
    qf[kc] = *(const bf16x8*)&qbase[(size_t)qrow * 128 + kc * 32 + quad * 8];
  f32x4 z4 = {0.f, 0.f, 0.f, 0.f};
  f32x4 o[8];
#pragma unroll
  for (int i = 0; i < 8; ++i) o[i] = z4;
  float mrow = -3e38f, lrow = 0.f;
  int ntiles = qt + 1;            // 64-key tiles
  int half0 = (ntiles + 1) >> 1;
  int jlo = split ? half0 : 0;
  int jhi = split ? ntiles : half0;
  if (jlo < jhi) {                // prologue: issue K then V for first tile
    STAGE_K(jlo);
    STAGE_V(jlo);
  }
  for (int j = jlo; j < jhi; ++j) {
    asm volatile("s_waitcnt vmcnt(4)" ::: "memory");
    __builtin_amdgcn_s_barrier();            // all waves: Ks ready
    __builtin_amdgcn_sched_barrier(0);
    f32x4 sa[4];
#pragma unroll
    for (int i = 0; i < 4; ++i) sa[i] = z4;
    __builtin_amdgcn_s_setprio(1);
#pragma unroll
    for (int kc = 0; kc < 4; ++kc) {
#pragma unroll
      for (int ni = 0; ni < 4; ++ni) {
        bf16x8 kf = *(const bf16x8*)&Ks[kc * 2048 + (ni * 16 + l16) * 32 + sl];
        sa[ni] = __builtin_amdgcn_mfma_f32_16x16x32_bf16(kf, qf[kc], sa[ni], 0, 0, 0);
      }
    }
    __builtin_amdgcn_s_setprio(0);
    asm volatile("s_waitcnt vmcnt(0)" ::: "memory");
    __builtin_amdgcn_s_barrier();            // all waves: Vs ready, Ks free
    __builtin_amdgcn_sched_barrier(0);
    if (j + 1 < jhi) STAGE_K(j + 1);         // hides under softmax+PV
    bool diag = (j == qt);
    float vmax = -3e38f;
#pragma unroll
    for (int ni = 0; ni < 4; ++ni)
#pragma unroll
      for (int r = 0; r < 4; ++r) {
        int key = j * 64 + ni * 16 + quad * 4 + r;
        float v = sa[ni][r];
        if (diag && key > qrow) v = -1e10f;
        sa[ni][r] = v;
        vmax = fmaxf(vmax, v);
      }
    vmax = fmaxf(vmax, __shfl_xor(vmax, 16));
    vmax = fmaxf(vmax, __shfl_xor(vmax, 32));
    float mnew = fmaxf(mrow, vmax);
    float alpha = exp2f(mrow - mnew);
    mrow = mnew;
    float rsum = 0.f;
#pragma unroll
    for (int ni = 0; ni < 4; ++ni)
#pragma unroll
      for (int r = 0; r < 4; ++r) {
        float p = exp2f(sa[ni][r] - mnew);
        sa[ni][r] = p;
        rsum += p;
      }
    rsum += __shfl_xor(rsum, 16);
    rsum += __shfl_xor(rsum, 32);
    lrow = lrow * alpha + rsum;
    float ar[4];
#pragma unroll
    for (int r = 0; r < 4; ++r) ar[r] = __shfl(alpha, quad * 4 + r);
#pragma unroll
    for (int nd = 0; nd < 8; ++nd)
#pragma unroll
      for (int r = 0; r < 4; ++r) o[nd][r] *= ar[r];
    __builtin_amdgcn_s_setprio(1);
#pragma unroll
    for (int ni = 0; ni < 4; ++ni) {
      s16x4 pf;
#pragma unroll
      for (int r = 0; r < 4; ++r) {
        __bf16 pb = (__bf16)sa[ni][r];   // native cast -> v_cvt_pk_bf16_f32 (RNE)
        pf[r] = __builtin_bit_cast(short, pb);
      }
      int chunk8 = (ni & 1) * 2 + (quad >> 1);
      int sub = (quad & 1) * 4;
      int kcv = ni >> 1;
#pragma unroll
      for (int nd = 0; nd < 8; ++nd) {
        int d = nd * 16 + l16;
        int slot = chunk8 ^ ((d >> 1) & 3);
        s16x4 vf = *(const s16x4*)&Vs[kcv * 4096 + d * 32 + slot * 8 + sub];
        o[nd] = __builtin_amdgcn_mfma_f32_16x16x16bf16_1k(pf, vf, o[nd], 0, 0, 0);
      }
    }
    __builtin_amdgcn_s_setprio(0);
    __builtin_amdgcn_s_barrier();            // all waves: Vs reads done
    __builtin_amdgcn_sched_barrier(0);
    if (j + 1 < jhi) STAGE_V(j + 1);         // hides under next QK
  }
  float mr[4], lr[4];
#pragma unroll
  for (int r = 0; r < 4; ++r) {
    mr[r] = __shfl(mrow, quad * 4 + r);
    lr[r] = __shfl(lrow, quad * 4 + r);
  }
  size_t pbase = (size_t)(split * 8 + h) * 4096 + qt * 64;
#pragma unroll
  for (int r = 0; r < 4; ++r) {
    int lrw = w * 16 + quad * 4 + r;
#pragma unroll
    for (int nd = 0; nd < 8; ++nd)
      Opart[(pbase + lrw) * 128 + nd * 16 + l16] = f2bf(o[nd][r]);
    if (l16 == 0) {
      mpart[pbase + lrw] = mr[r];
      lpart[pbase + lrw] = lr[r];
    }
  }
}

// ---------------- combine the two key-splits ----------------
__global__ __launch_bounds__(256) void combine(const unsigned short* Opart, const float* mpart,
                                               const float* lpart, unsigned short* attn) {
  int idx = blockIdx.x * 256 + threadIdx.x;  // 8*4096*128
  int h = idx >> 19;
  int rem = idx & 524287;
  int row = rem >> 7, d = rem & 127;
  int r0 = h * 4096 + row;
  int r1 = 32768 + r0;
  float m0 = mpart[r0], m1 = mpart[r1];
  float l0 = lpart[r0], l1 = lpart[r1];
  float m = fmaxf(m0, m1);
  float a0 = exp2f(m0 - m), a1 = exp2f(m1 - m);
  float o0 = bf2f(Opart[(size_t)r0 * 128 + d]);
  float o1 = bf2f(Opart[(size_t)r1 * 128 + d]);
  float denom = a0 * l0 + a1 * l1;
  attn[(size_t)row * 1024 + h * 128 + d] = f2bf((a0 * o0 + a1 * o1) / denom);
}

// ---------------- rep-logit tile scores (XCD-pinned: x = head) ----------------
__global__ __launch_bounds__(256) void rep_scores(const float* krope, const float* qrep,
                                                  const float* cosb, const float* sinb,
                                                  float* scores) {
  int h = blockIdx.x, tt = blockIdx.y;
  int tid = threadIdx.x;
  __shared__ float Kt[128 * 129];
  __shared__ float qv[32 * 128];
  __shared__ float lg[32 * 128];
  for (int idx = tid; idx < 16384; idx += 256) {
    int r = idx >> 7, c = idx & 127;
    Kt[r * 129 + c] = krope[(size_t)(tt * 128 + r) * 1024 + h * 128 + c];
  }
  for (int idx = tid; idx < 2048; idx += 256) {
    int rep = idx >> 6, j = idx & 63;
    int sq = rep * 128 + 127;
    float a = qrep[(size_t)rep * 1024 + h * 128 + j];
    float b = qrep[(size_t)rep * 1024 + h * 128 + j + 64];
    float c = cosb[sq * 64 + j], sn = sinb[sq * 64 + j];
    qv[rep * 128 + j]      = a * c - b * sn;
    qv[rep * 128 + j + 64] = b * c + a * sn;
  }
  __syncthreads();
  int key = tid >> 1, half = tid & 1;
  float kreg[64];
#pragma unroll
  for (int d = 0; d < 64; ++d) kreg[d] = Kt[key * 129 + half * 64 + d];
  for (int rep = 0; rep < 32; ++rep) {
    const float* q = &qv[rep * 128 + half * 64];
    float dot = 0.f;
#pragma unroll
    for (int d = 0; d < 64; ++d) dot += kreg[d] * q[d];
    dot += __shfl_xor(dot, 1);
    if (half == 0) lg[rep * 128 + key] = dot;
  }
  __syncthreads();
  int rep = tid >> 3, chunk = tid & 7;
  float m = -3e38f;
#pragma unroll
  for (int i = 0; i < 16; ++i) m = fmaxf(m, lg[rep * 128 + chunk * 16 + i]);
  m = fmaxf(m, __shfl_xor(m, 1));
  m = fmaxf(m, __shfl_xor(m, 2));
  m = fmaxf(m, __shfl_xor(m, 4));
  if (chunk == 0) scores[((size_t)h * 32 + rep) * 32 + tt] = m;
}

// ---------------- top-8 selection ----------------
__global__ __launch_bounds__(256) void select_topk(const float* scores, float* out_idx) {
  int tid = threadIdx.x;
  int h = tid >> 5, t = tid & 31;
  float vals[32];
#pragma unroll
  for (int tt = 0; tt < 32; ++tt)
    vals[tt] = (tt <= t) ? scores[((size_t)h * 32 + t) * 32 + tt] : -3.0e38f;
  int base = (h * 32 + t) * 8;
  for (int i = 0; i < 8; ++i) {
    float best = -3.4e38f;
    int bi = 0;
#pragma unroll
    for (int c = 0; c < 32; ++c)
      if (vals[c] > best) { best = vals[c]; bi = c; }
    out_idx[base + i] = (float)bi;
    vals[bi] = -3.4e38f;
  }
}

extern "C" void kernel_launch(void* const* d_in, const int* in_sizes, int n_in,
                              void* d_out, int out_size, void* d_ws, size_t ws_size,
                              hipStream_t stream) {
  (void)in_sizes; (void)n_in; (void)out_size; (void)ws_size;
  const float* x    = (const float*)d_in[0];
  const float* wq   = (const float*)d_in[1];
  const float* wk   = (const float*)d_in[2];
  const float* wv   = (const float*)d_in[3];
  const float* wo   = (const float*)d_in[4];
  const float* cosb = (const float*)d_in[5];
  const float* sinb = (const float*)d_in[6];
  float* out = (float*)d_out;
  char* ws = (char*)d_ws;

  unsigned short* x_bf   = (unsigned short*)(ws);              //  0 ..  8 MB (= xh plane)
  unsigned short* wT     = (unsigned short*)(ws + 8388608);    //  8 .. 14 MB (wq|wv|wkh)
  unsigned short* woT    = (unsigned short*)(ws + 14680064);   // 14 .. 16 MB
  unsigned short* qv_bf  = (unsigned short*)(ws + 16777216);   // 16 .. 32 MB (dead after rope_pack)
  unsigned short* attn   = (unsigned short*)(ws + 16777216);   // 16 .. 24 MB
  unsigned short* Opart  = (unsigned short*)(ws + 25165824);   // 24 .. 40 MB (2x8x4096x128 bf16)
  unsigned short* q_bf   = (unsigned short*)(ws + 41943040);   // 40 .. 48 MB
  unsigned short* k_bf   = (unsigned short*)(ws + 50331648);   // 48 .. 56 MB
  unsigned short* vT     = (unsigned short*)(ws + 58720256);   // 56 .. 64 MB
  unsigned short* xm     = (unsigned short*)(ws + 41943040);   // transient, overlaps q_bf
  unsigned short* wkm    = (unsigned short*)(ws + 58720256);   // transient, overlaps vT
  float*          kf32   = (float*)(ws + 67108864);            // 64 .. 80 MB
  float*          xrep   = (float*)(ws + 83886080);            // 80.00 MB
  float*          qrep   = (float*)(ws + 84017152);            // 80.125 MB
  float*          qparts = (float*)(ws + 84148224);            // 80.25 .. 81.25 MB
  float*          scores = (float*)(ws + 85196800);            // 81.25 MB + 32 KB
  float*          mpart  = (float*)(ws + 85229568);            // +256 KB
  float*          lpart  = (float*)(ws + 85491712);            // +256 KB

  unsigned short* wkh = wT + (size_t)2 * 1024 * 1024;

  conv_w<<<dim3(32, 32, 4), 256, 0, stream>>>(wq, wk, wv, wo, wT, woT, wkm);
  conv_x<<<dim3(16384), 256, 0, stream>>>(x, x_bf, xm, xrep);
  qv_kexact<<<dim3(1024), 256, 0, stream>>>(x_bf, xm, wT, wkh, wkm, cosb, sinb, qv_bf, kf32, k_bf);
  qrep_gemm<<<dim3(32, 8), 256, 0, stream>>>(xrep, wq, qparts);
  qsum<<<dim3(128), 256, 0, stream>>>(qparts, qrep);
  rope_pack<<<dim3(64, 8), 256, 0, stream>>>(qv_bf, cosb, sinb, q_bf, vT);
  flash_attn<<<dim3(8, 64, 2), 256, 0, stream>>>(q_bf, k_bf, vT, Opart, mpart, lpart);
  combine<<<dim3(16384), 256, 0, stream>>>(Opart, mpart, lpart, attn);
  gemm_bt64<<<dim3(8, 64), 256, 0, stream>>>(attn, woT, out);
  rep_scores<<<dim3(8, 32), 256, 0, stream>>>(kf32, qrep, cosb, sinb, scores);
  select_topk<<<dim3(1), 256, 0, stream>>>(scores, out + 4194304);
}

// Round 10
// 333.964 us; speedup vs baseline: 1.0038x; 1.0038x over previous
//
#include <hip/hip_runtime.h>
#include <hip/hip_bf16.h>
#include <stdint.h>

#define S_LEN 4096
#define EMB   1024
#define NH    8
#define HD    128

typedef __bf16 bf16x8 __attribute__((ext_vector_type(8)));
typedef float  f32x4  __attribute__((ext_vector_type(4)));
typedef short  s16x4  __attribute__((ext_vector_type(4)));

__device__ __forceinline__ unsigned short f2bf(float f) {
  unsigned int u = __float_as_uint(f);
  u += 0x7fffu + ((u >> 16) & 1u);
  return (unsigned short)(u >> 16);
}
__device__ __forceinline__ float bf2f(unsigned short u) {
  return __uint_as_float(((unsigned int)u) << 16);
}

typedef __attribute__((address_space(3))) void lds_void_t;
typedef const __attribute__((address_space(1))) void gbl_void_t;

__device__ __forceinline__ void load_lds16(const void* g, void* l) {
  __builtin_amdgcn_global_load_lds((gbl_void_t*)g, (lds_void_t*)l, 16, 0, 0);
}

// ---------------- weight transpose+convert ----------------
// wT layout: [0,1M)=wq^T, [1M,2M)=wv^T  (the 2048-wide QV GEMM B);  [2M,3M)=wk^T (kexact)
__global__ __launch_bounds__(256) void conv_w(const float* wq, const float* wk, const float* wv,
                                              const float* wo, unsigned short* wT, unsigned short* woT,
                                              unsigned short* wkm) {
  int z = blockIdx.z;
  const float* src = (z == 0) ? wq : (z == 1) ? wk : (z == 2) ? wv : wo;
  unsigned short* dst = (z == 0) ? wT
                      : (z == 2) ? wT + (size_t)1 * 1024 * 1024
                      : (z == 1) ? wT + (size_t)2 * 1024 * 1024
                                 : woT;
  __shared__ float tl[32][33];
  int tx = threadIdx.x & 31, ty = threadIdx.x >> 5;
  int c0 = blockIdx.x * 32, r0 = blockIdx.y * 32;
#pragma unroll
  for (int i = 0; i < 4; ++i)
    tl[ty + 8 * i][tx] = src[(size_t)(r0 + ty + 8 * i) * 1024 + c0 + tx];
  __syncthreads();
#pragma unroll
  for (int i = 0; i < 4; ++i) {
    float v = tl[tx][ty + 8 * i];
    unsigned short h = f2bf(v);
    size_t o = (size_t)(c0 + ty + 8 * i) * 1024 + r0 + tx;
    dst[o] = h;
    if (z == 1) wkm[o] = f2bf(v - bf2f(h));
  }
}

// ---------------- x convert (2-plane split) + rep-row gather ----------------
__global__ __launch_bounds__(256) void conv_x(const float* x, unsigned short* xh, unsigned short* xm,
                                              float* xrep) {
  int idx = blockIdx.x * 256 + threadIdx.x;
  if (idx < 4194304) {
    float v = x[idx];
    unsigned short h = f2bf(v);
    xh[idx] = h;
    xm[idx] = f2bf(v - bf2f(h));
  }
  if (idx < 32768) {
    int r = idx >> 10, e = idx & 1023;
    xrep[idx] = x[(size_t)(r * 128 + 127) * 1024 + e];
  }
}

// ---------------- bf16 MFMA GEMM: C[M,N] = A[M,K=1024] * B[N,K=1024]^T ----------------
template <bool BF16OUT>
__global__ __launch_bounds__(256) void gemm_bt(const unsigned short* A, const unsigned short* B,
                                               void* Cv, int N) {
  __shared__ unsigned short Asm[4096];
  __shared__ unsigned short Bsm[4096];
  int tid = threadIdx.x;
  int w = tid >> 6, l = tid & 63, quad = l >> 4, l16 = l & 15;
  int wm = w >> 1, wn = w & 1;
  int m0 = blockIdx.y * 128, n0 = blockIdx.x * 128;
  f32x4 acc[4][4];
  f32x4 z4 = {0.f, 0.f, 0.f, 0.f};
#pragma unroll
  for (int i = 0; i < 4; ++i)
#pragma unroll
    for (int j = 0; j < 4; ++j) acc[i][j] = z4;
  const unsigned short* Ag = A + (size_t)m0 * 1024;
  const unsigned short* Bg = B + (size_t)n0 * 1024;
  int sl = (quad ^ ((l16 >> 1) & 3)) * 8;
  for (int kt = 0; kt < 1024; kt += 32) {
#pragma unroll
    for (int it = 0; it < 2; ++it) {
      int c = it * 256 + tid;
      int row = c >> 2, sg = c & 3;
      int sw = (sg ^ ((row >> 1) & 3)) * 8;
      load_lds16(Ag + (size_t)row * 1024 + kt + sw, &Asm[(it * 256 + (tid & 192)) * 8]);
      load_lds16(Bg + (size_t)row * 1024 + kt + sw, &Bsm[(it * 256 + (tid & 192)) * 8]);
    }
    __syncthreads();
    bf16x8 af[4], bfr[4];
#pragma unroll
    for (int i = 0; i < 4; ++i) {
      af[i]  = *(const bf16x8*)&Asm[(wm * 64 + i * 16 + l16) * 32 + sl];
      bfr[i] = *(const bf16x8*)&Bsm[(wn * 64 + i * 16 + l16) * 32 + sl];
    }
#pragma unroll
    for (int mi = 0; mi < 4; ++mi)
#pragma unroll
      for (int ni = 0; ni < 4; ++ni)
        acc[mi][ni] = __builtin_amdgcn_mfma_f32_16x16x32_bf16(af[mi], bfr[ni], acc[mi][ni], 0, 0, 0);
    __syncthreads();
  }
#pragma unroll
  for (int mi = 0; mi < 4; ++mi)
#pragma unroll
    for (int ni = 0; ni < 4; ++ni)
#pragma unroll
      for (int r = 0; r < 4; ++r) {
        int row = m0 + wm * 64 + mi * 16 + quad * 4 + r;
        int col = n0 + wn * 64 + ni * 16 + l16;
        if (BF16OUT)
          ((unsigned short*)Cv)[(size_t)row * N + col] = f2bf(acc[mi][ni][r]);
        else
          ((float*)Cv)[(size_t)row * N + col] = acc[mi][ni][r];
      }
}

// ---------------- 64x128-tile fp32-out GEMM (2 blocks/CU for the out-projection) ----------------
__global__ __launch_bounds__(256) void gemm_bt64(const unsigned short* A, const unsigned short* B,
                                                 float* C) {
  __shared__ unsigned short As[2048];   // 64x32
  __shared__ unsigned short Bs[4096];   // 128x32
  int tid = threadIdx.x;
  int w = tid >> 6, l = tid & 63, quad = l >> 4, l16 = l & 15;
  int wm = w >> 1, wn = w & 1;
  int m0 = blockIdx.y * 64, n0 = blockIdx.x * 128;
  f32x4 acc[2][4];
  f32x4 z4 = {0.f, 0.f, 0.f, 0.f};
#pragma unroll
  for (int i = 0; i < 2; ++i)
#pragma unroll
    for (int j = 0; j < 4; ++j) acc[i][j] = z4;
  const unsigned short* Ag = A + (size_t)m0 * 1024;
  const unsigned short* Bg = B + (size_t)n0 * 1024;
  int arow = tid >> 2, asg = tid & 3;
  int asw = (asg ^ ((arow >> 1) & 3)) * 8;
  int sl = (quad ^ ((l16 >> 1) & 3)) * 8;
  for (int kt = 0; kt < 1024; kt += 32) {
    load_lds16(Ag + (size_t)arow * 1024 + kt + asw, &As[(tid & 192) * 8]);
#pragma unroll
    for (int it = 0; it < 2; ++it) {
      int c = it * 256 + tid;
      int row = c >> 2, sg = c & 3;
      int sw = (sg ^ ((row >> 1) & 3)) * 8;
      load_lds16(Bg + (size_t)row * 1024 + kt + sw, &Bs[(it * 256 + (tid & 192)) * 8]);
    }
    __syncthreads();
    bf16x8 af[2], bfr[4];
#pragma unroll
    for (int i = 0; i < 2; ++i)
      af[i] = *(const bf16x8*)&As[(wm * 32 + i * 16 + l16) * 32 + sl];
#pragma unroll
    for (int j = 0; j < 4; ++j)
      bfr[j] = *(const bf16x8*)&Bs[(wn * 64 + j * 16 + l16) * 32 + sl];
#pragma unroll
    for (int mi = 0; mi < 2; ++mi)
#pragma unroll
      for (int ni = 0; ni < 4; ++ni)
        acc[mi][ni] = __builtin_amdgcn_mfma_f32_16x16x32_bf16(af[mi], bfr[ni], acc[mi][ni], 0, 0, 0);
    __syncthreads();
  }
#pragma unroll
  for (int mi = 0; mi < 2; ++mi)
#pragma unroll
    for (int ni = 0; ni < 4; ++ni)
#pragma unroll
      for (int r = 0; r < 4; ++r) {
        int row = m0 + wm * 32 + mi * 16 + quad * 4 + r;
        int col = n0 + wn * 64 + ni * 16 + l16;
        C[(size_t)row * 1024 + col] = acc[mi][ni][r];
      }
}

// ---------------- exact K-GEMM (2-plane split MFMA) + fused RoPE epilogue ----------------
__global__ __launch_bounds__(256) void kexact(const unsigned short* Ah, const unsigned short* Am,
                                              const unsigned short* Bh, const unsigned short* Bm,
                                              const float* cosb, const float* sinb,
                                              float* C, unsigned short* k_bf) {
  __shared__ unsigned short As[2 * 2048];
  __shared__ unsigned short Bs[2 * 4096];
  int tid = threadIdx.x;
  int w = tid >> 6, l = tid & 63, quad = l >> 4, l16 = l & 15;
  int wm = w >> 1, wn = w & 1;
  int m0 = blockIdx.y * 64, n0 = blockIdx.x * 128;
  f32x4 acc[2][4];
  f32x4 z4 = {0.f, 0.f, 0.f, 0.f};
#pragma unroll
  for (int i = 0; i < 2; ++i)
#pragma unroll
    for (int j = 0; j < 4; ++j) acc[i][j] = z4;
  const unsigned short* Aps[2] = {Ah + (size_t)m0 * 1024, Am + (size_t)m0 * 1024};
  const unsigned short* Bps[2] = {Bh + (size_t)n0 * 1024, Bm + (size_t)n0 * 1024};
  int arow = tid >> 2, asg = tid & 3;
  int asw = (asg ^ ((arow >> 1) & 3)) * 8;
  int sl = (quad ^ ((l16 >> 1) & 3)) * 8;
  for (int kt = 0; kt < 1024; kt += 32) {
#pragma unroll
    for (int p = 0; p < 2; ++p) {
      load_lds16(Aps[p] + (size_t)arow * 1024 + kt + asw, &As[p * 2048 + (tid & 192) * 8]);
#pragma unroll
      for (int it = 0; it < 2; ++it) {
        int c = it * 256 + tid;
        int row = c >> 2, sg = c & 3;
        int sw = (sg ^ ((row >> 1) & 3)) * 8;
        load_lds16(Bps[p] + (size_t)row * 1024 + kt + sw,
                   &Bs[p * 4096 + (it * 256 + (tid & 192)) * 8]);
      }
    }
    __syncthreads();
    bf16x8 af[2][2], bfr[2][4];
#pragma unroll
    for (int p = 0; p < 2; ++p) {
#pragma unroll
      for (int i = 0; i < 2; ++i)
        af[p][i] = *(const bf16x8*)&As[p * 2048 + (wm * 32 + i * 16 + l16) * 32 + sl];
#pragma unroll
      for (int j = 0; j < 4; ++j)
        bfr[p][j] = *(const bf16x8*)&Bs[p * 4096 + (wn * 64 + j * 16 + l16) * 32 + sl];
    }
#pragma unroll
    for (int mi = 0; mi < 2; ++mi)
#pragma unroll
      for (int ni = 0; ni < 4; ++ni) {
        f32x4 a = acc[mi][ni];
        a = __builtin_amdgcn_mfma_f32_16x16x32_bf16(af[0][mi], bfr[0][ni], a, 0, 0, 0); // hh
        a = __builtin_amdgcn_mfma_f32_16x16x32_bf16(af[0][mi], bfr[1][ni], a, 0, 0, 0); // hm
        a = __builtin_amdgcn_mfma_f32_16x16x32_bf16(af[1][mi], bfr[0][ni], a, 0, 0, 0); // mh
        a = __builtin_amdgcn_mfma_f32_16x16x32_bf16(af[1][mi], bfr[1][ni], a, 0, 0, 0); // mm
        acc[mi][ni] = a;
      }
    __syncthreads();
  }
  // -------- fused RoPE epilogue --------
  float* BsF = (float*)Bs;  // 64x64 fp32 = 16KB b-half exchange
  if (wn == 1) {
#pragma unroll
    for (int mi = 0; mi < 2; ++mi)
#pragma unroll
      for (int ni = 0; ni < 4; ++ni)
#pragma unroll
        for (int r = 0; r < 4; ++r)
          BsF[(wm * 32 + mi * 16 + quad * 4 + r) * 64 + ni * 16 + l16] = acc[mi][ni][r];
  }
  __syncthreads();
  if (wn == 0) {
    int h = blockIdx.x;
#pragma unroll
    for (int mi = 0; mi < 2; ++mi)
#pragma unroll
      for (int ni = 0; ni < 4; ++ni)
#pragma unroll
        for (int r = 0; r < 4; ++r) {
          int rl = wm * 32 + mi * 16 + quad * 4 + r;
          int j  = ni * 16 + l16;
          int s  = m0 + rl;
          float a = acc[mi][ni][r];
          float b = BsF[rl * 64 + j];
          float c = cosb[s * 64 + j], sn = sinb[s * 64 + j];
          float a2 = a * c - b * sn;
          float b2 = b * c + a * sn;
          size_t e = (size_t)s * 1024 + h * 128 + j;
          C[e]      = a2;
          C[e + 64] = b2;
          size_t kb = ((size_t)h * S_LEN + s) * 128 + j;
          k_bf[kb]      = f2bf(a2);
          k_bf[kb + 64] = f2bf(b2);
        }
  }
}

// ---------------- qrep GEMM ----------------
__global__ __launch_bounds__(256) void qrep_gemm(const float* xrep, const float* wq, float* qparts) {
  int n0 = blockIdx.x * 32;
  int p  = blockIdx.y;
  int k0 = p * 128;
  int tid = threadIdx.x;
  __shared__ float xs[32 * 132];
  __shared__ float wsm[128 * 36];
#pragma unroll
  for (int i = 0; i < 4; ++i) {
    int c = tid + 256 * i;
    int m = c >> 5, kc = (c & 31) * 4;
    *(f32x4*)&xs[m * 132 + kc] = *(const f32x4*)&xrep[(size_t)m * 1024 + k0 + kc];
  }
#pragma unroll
  for (int i = 0; i < 4; ++i) {
    int c = tid + 256 * i;
    int k = c >> 3, n = (c & 7) * 4;
    *(f32x4*)&wsm[k * 36 + n] = *(const f32x4*)&wq[(size_t)(k0 + k) * 1024 + n0 + n];
  }
  __syncthreads();
#pragma unroll
  for (int i = 0; i < 4; ++i) {
    int o = tid + 256 * i;
    int m = o >> 5, n = o & 31;
    float acc = 0.f;
#pragma unroll 16
    for (int k = 0; k < 128; ++k) acc += xs[m * 132 + k] * wsm[k * 36 + n];
    qparts[((size_t)p * 32 + m) * 1024 + n0 + n] = acc;
  }
}

__global__ __launch_bounds__(256) void qsum(const float* qparts, float* qrep) {
  int i = blockIdx.x * 256 + threadIdx.x;
  float s = 0.f;
#pragma unroll
  for (int p = 0; p < 8; ++p) s += qparts[(size_t)p * 32768 + i];
  qrep[i] = s;
}

// ---------------- RoPE + pack: q (pre-scaled) + v-transpose from the 2048-wide QV buffer ----------------
__global__ __launch_bounds__(256) void rope_pack(const unsigned short* qv, const float* cosb,
                                                 const float* sinb, unsigned short* q_bf,
                                                 unsigned short* vT) {
  int h = blockIdx.y;
  int s0 = blockIdx.x * 64;
  int tid = threadIdx.x;
  const float sc2 = 0.12751712f;  // (1/sqrt(128)) * log2(e), folded into q
  __shared__ unsigned short vt[128 * 66];
  for (int idx = tid; idx < 4096; idx += 256) {
    int r = idx >> 6, j = idx & 63;
    int s = s0 + r;
    float c = cosb[s * 64 + j], sn = sinb[s * 64 + j];
    const unsigned short* row = qv + (size_t)s * 2048 + h * 128;
    size_t ob = ((size_t)h * S_LEN + s) * 128;
    float a = bf2f(row[j]), b = bf2f(row[j + 64]);
    q_bf[ob + j]      = f2bf((a * c - b * sn) * sc2);
    q_bf[ob + j + 64] = f2bf((b * c + a * sn) * sc2);
  }
  for (int idx = tid; idx < 8192; idx += 256) {
    int r = idx >> 7, d = idx & 127;
    vt[d * 66 + r] = qv[(size_t)(s0 + r) * 2048 + 1024 + h * 128 + d];
  }
  __syncthreads();
  for (int idx = tid; idx < 8192; idx += 256) {
    int d = idx >> 6, c = idx & 63;
    vT[((size_t)h * 128 + d) * S_LEN + s0 + c] = vt[d * 66 + c];
  }
}

// ---------------- flash attention: transposed-S, register P, K-tile 64 ----------------
// R10: 3-way key split (grid 8x64x3 = 1536 blocks, 6/CU) to fix the 24%-occupancy load
// imbalance (work ~ qt, 1024 blocks left CUs half-empty). Counted-vmcnt pipeline kept.
#define STAGE_K(jj)                                                          \
  {                                                                          \
    _Pragma("unroll")                                                        \
    for (int it = 0; it < 4; ++it) {                                         \
      int c = it * 256 + tid;                                                \
      int kc = c >> 8, cc = c & 255, key = cc >> 2, sg = cc & 3;             \
      int sw = (sg ^ ((key >> 1) & 3)) * 8;                                  \
      load_lds16(kbase + (size_t)((jj) * 64 + key) * 128 + kc * 32 + sw,     \
                 &Ks[(it * 256 + (tid & 192)) * 8]);                         \
    }                                                                        \
  }
#define STAGE_V(jj)                                                          \
  {                                                                          \
    _Pragma("unroll")                                                        \
    for (int it = 0; it < 4; ++it) {                                         \
      int c = it * 256 + tid;                                                \
      int kcv = c >> 9, ccv = c & 511, d = ccv >> 2, sgv = c & 3;            \
      int swv = (sgv ^ ((d >> 1) & 3)) * 8;                                  \
      load_lds16(vbase + (size_t)d * S_LEN + (jj) * 64 + kcv * 32 + swv,     \
                 &Vs[(it * 256 + (tid & 192)) * 8]);                         \
    }                                                                        \
  }

__global__ __launch_bounds__(256, 4) void flash_attn(const unsigned short* q_bf,
                                                     const unsigned short* k_bf,
                                                     const unsigned short* vT,
                                                     unsigned short* Opart,
                                                     float* mpart, float* lpart) {
  int h = blockIdx.x;
  int y = blockIdx.y;
  int qt = (y < 32) ? y : 95 - y;
  int split = blockIdx.z;
  int tid = threadIdx.x, w = tid >> 6, l = tid & 63, quad = l >> 4, l16 = l & 15;
  __shared__ unsigned short Ks[8192]; // 16KB: [kc4(dim)][key64][32dims] swizzled
  __shared__ unsigned short Vs[8192]; // 16KB: [kc2(key)][d128][32keys] swizzled
  const unsigned short* qbase = q_bf + (size_t)h * S_LEN * 128;
  const unsigned short* kbase = k_bf + (size_t)h * S_LEN * 128;
  const unsigned short* vbase = vT + (size_t)h * 128 * S_LEN;
  int sl = (quad ^ ((l16 >> 1) & 3)) * 8;
  int qrow = qt * 64 + w * 16 + l16;
  bf16x8 qf[4];
#pragma unroll
  for (int kc = 0; kc < 4; ++kc)
    qf[kc] = *(const bf16x8*)&qbase[(size_t)qrow * 128 + kc * 32 + quad * 8];
  f32x4 z4 = {0.f, 0.f, 0.f, 0.f};
  f32x4 o[8];
#pragma unroll
  for (int i = 0; i < 8; ++i) o[i] = z4;
  float mrow = -3e38f, lrow = 0.f;
  int ntiles = qt + 1;                 // 64-key tiles
  int jlo = (split * ntiles) / 3;
  int jhi = ((split + 1) * ntiles) / 3;
  if (jlo < jhi) {                     // prologue: issue K then V for first tile
    STAGE_K(jlo);
    STAGE_V(jlo);
  }
  for (int j = jlo; j < jhi; ++j) {
    asm volatile("s_waitcnt vmcnt(4)" ::: "memory");
    __builtin_amdgcn_s_barrier();            // all waves: Ks ready
    __builtin_amdgcn_sched_barrier(0);
    f32x4 sa[4];
#pragma unroll
    for (int i = 0; i < 4; ++i) sa[i] = z4;
    __builtin_amdgcn_s_setprio(1);
#pragma unroll
    for (int kc = 0; kc < 4; ++kc) {
#pragma unroll
      for (int ni = 0; ni < 4; ++ni) {
        bf16x8 kf = *(const bf16x8*)&Ks[kc * 2048 + (ni * 16 + l16) * 32 + sl];
        sa[ni] = __builtin_amdgcn_mfma_f32_16x16x32_bf16(kf, qf[kc], sa[ni], 0, 0, 0);
      }
    }
    __builtin_amdgcn_s_setprio(0);
    asm volatile("s_waitcnt vmcnt(0)" ::: "memory");
    __builtin_amdgcn_s_barrier();            // all waves: Vs ready, Ks free
    __builtin_amdgcn_sched_barrier(0);
    if (j + 1 < jhi) STAGE_K(j + 1);         // hides under softmax+PV
    bool diag = (j == qt);
    float vmax = -3e38f;
#pragma unroll
    for (int ni = 0; ni < 4; ++ni)
#pragma unroll
      for (int r = 0; r < 4; ++r) {
        int key = j * 64 + ni * 16 + quad * 4 + r;
        float v = sa[ni][r];
        if (diag && key > qrow) v = -1e10f;
        sa[ni][r] = v;
        vmax = fmaxf(vmax, v);
      }
    vmax = fmaxf(vmax, __shfl_xor(vmax, 16));
    vmax = fmaxf(vmax, __shfl_xor(vmax, 32));
    float mnew = fmaxf(mrow, vmax);
    float alpha = exp2f(mrow - mnew);
    mrow = mnew;
    float rsum = 0.f;
#pragma unroll
    for (int ni = 0; ni < 4; ++ni)
#pragma unroll
      for (int r = 0; r < 4; ++r) {
        float p = exp2f(sa[ni][r] - mnew);
        sa[ni][r] = p;
        rsum += p;
      }
    rsum += __shfl_xor(rsum, 16);
    rsum += __shfl_xor(rsum, 32);
    lrow = lrow * alpha + rsum;
    float ar[4];
#pragma unroll
    for (int r = 0; r < 4; ++r) ar[r] = __shfl(alpha, quad * 4 + r);
#pragma unroll
    for (int nd = 0; nd < 8; ++nd)
#pragma unroll
      for (int r = 0; r < 4; ++r) o[nd][r] *= ar[r];
    __builtin_amdgcn_s_setprio(1);
#pragma unroll
    for (int ni = 0; ni < 4; ++ni) {
      s16x4 pf;
#pragma unroll
      for (int r = 0; r < 4; ++r) {
        __bf16 pb = (__bf16)sa[ni][r];   // native cast -> v_cvt_pk_bf16_f32 (RNE)
        pf[r] = __builtin_bit_cast(short, pb);
      }
      int chunk8 = (ni & 1) * 2 + (quad >> 1);
      int sub = (quad & 1) * 4;
      int kcv = ni >> 1;
#pragma unroll
      for (int nd = 0; nd < 8; ++nd) {
        int d = nd * 16 + l16;
        int slot = chunk8 ^ ((d >> 1) & 3);
        s16x4 vf = *(const s16x4*)&Vs[kcv * 4096 + d * 32 + slot * 8 + sub];
        o[nd] = __builtin_amdgcn_mfma_f32_16x16x16bf16_1k(pf, vf, o[nd], 0, 0, 0);
      }
    }
    __builtin_amdgcn_s_setprio(0);
    __builtin_amdgcn_s_barrier();            // all waves: Vs reads done
    __builtin_amdgcn_sched_barrier(0);
    if (j + 1 < jhi) STAGE_V(j + 1);         // hides under next QK
  }
  float mr[4], lr[4];
#pragma unroll
  for (int r = 0; r < 4; ++r) {
    mr[r] = __shfl(mrow, quad * 4 + r);
    lr[r] = __shfl(lrow, quad * 4 + r);
  }
  size_t pbase = (size_t)(split * 8 + h) * 4096 + qt * 64;
#pragma unroll
  for (int r = 0; r < 4; ++r) {
    int lrw = w * 16 + quad * 4 + r;
#pragma unroll
    for (int nd = 0; nd < 8; ++nd)
      Opart[(pbase + lrw) * 128 + nd * 16 + l16] = f2bf(o[nd][r]);
    if (l16 == 0) {
      mpart[pbase + lrw] = mr[r];
      lpart[pbase + lrw] = lr[r];
    }
  }
}

// ---------------- combine the three key-splits ----------------
__global__ __launch_bounds__(256) void combine(const unsigned short* Opart, const float* mpart,
                                               const float* lpart, unsigned short* attn) {
  int idx = blockIdx.x * 256 + threadIdx.x;  // 8*4096*128
  int h = idx >> 19;
  int rem = idx & 524287;
  int row = rem >> 7, d = rem & 127;
  int r0 = h * 4096 + row;
  int r1 = 32768 + r0;
  int r2 = 65536 + r0;
  float m0 = mpart[r0], m1 = mpart[r1], m2 = mpart[r2];
  float l0 = lpart[r0], l1 = lpart[r1], l2 = lpart[r2];
  float m = fmaxf(fmaxf(m0, m1), m2);
  float a0 = exp2f(m0 - m), a1 = exp2f(m1 - m), a2 = exp2f(m2 - m);
  float o0 = bf2f(Opart[(size_t)r0 * 128 + d]);
  float o1 = bf2f(Opart[(size_t)r1 * 128 + d]);
  float o2 = bf2f(Opart[(size_t)r2 * 128 + d]);
  float denom = a0 * l0 + a1 * l1 + a2 * l2;
  attn[(size_t)row * 1024 + h * 128 + d] = f2bf((a0 * o0 + a1 * o1 + a2 * o2) / denom);
}

// ---------------- rep-logit tile scores (XCD-pinned: x = head) ----------------
__global__ __launch_bounds__(256) void rep_scores(const float* krope, const float* qrep,
                                                  const float* cosb, const float* sinb,
                                                  float* scores) {
  int h = blockIdx.x, tt = blockIdx.y;
  int tid = threadIdx.x;
  __shared__ float Kt[128 * 129];
  __shared__ float qv[32 * 128];
  __shared__ float lg[32 * 128];
  for (int idx = tid; idx < 16384; idx += 256) {
    int r = idx >> 7, c = idx & 127;
    Kt[r * 129 + c] = krope[(size_t)(tt * 128 + r) * 1024 + h * 128 + c];
  }
  for (int idx = tid; idx < 2048; idx += 256) {
    int rep = idx >> 6, j = idx & 63;
    int sq = rep * 128 + 127;
    float a = qrep[(size_t)rep * 1024 + h * 128 + j];
    float b = qrep[(size_t)rep * 1024 + h * 128 + j + 64];
    float c = cosb[sq * 64 + j], sn = sinb[sq * 64 + j];
    qv[rep * 128 + j]      = a * c - b * sn;
    qv[rep * 128 + j + 64] = b * c + a * sn;
  }
  __syncthreads();
  int key = tid >> 1, half = tid & 1;
  float kreg[64];
#pragma unroll
  for (int d = 0; d < 64; ++d) kreg[d] = Kt[key * 129 + half * 64 + d];
  for (int rep = 0; rep < 32; ++rep) {
    const float* q = &qv[rep * 128 + half * 64];
    float dot = 0.f;
#pragma unroll
    for (int d = 0; d < 64; ++d) dot += kreg[d] * q[d];
    dot += __shfl_xor(dot, 1);
    if (half == 0) lg[rep * 128 + key] = dot;
  }
  __syncthreads();
  int rep = tid >> 3, chunk = tid & 7;
  float m = -3e38f;
#pragma unroll
  for (int i = 0; i < 16; ++i) m = fmaxf(m, lg[rep * 128 + chunk * 16 + i]);
  m = fmaxf(m, __shfl_xor(m, 1));
  m = fmaxf(m, __shfl_xor(m, 2));
  m = fmaxf(m, __shfl_xor(m, 4));
  if (chunk == 0) scores[((size_t)h * 32 + rep) * 32 + tt] = m;
}

// ---------------- top-8 selection ----------------
__global__ __launch_bounds__(256) void select_topk(const float* scores, float* out_idx) {
  int tid = threadIdx.x;
  int h = tid >> 5, t = tid & 31;
  float vals[32];
#pragma unroll
  for (int tt = 0; tt < 32; ++tt)
    vals[tt] = (tt <= t) ? scores[((size_t)h * 32 + t) * 32 + tt] : -3.0e38f;
  int base = (h * 32 + t) * 8;
  for (int i = 0; i < 8; ++i) {
    float best = -3.4e38f;
    int bi = 0;
#pragma unroll
    for (int c = 0; c < 32; ++c)
      if (vals[c] > best) { best = vals[c]; bi = c; }
    out_idx[base + i] = (float)bi;
    vals[bi] = -3.4e38f;
  }
}

extern "C" void kernel_launch(void* const* d_in, const int* in_sizes, int n_in,
                              void* d_out, int out_size, void* d_ws, size_t ws_size,
                              hipStream_t stream) {
  (void)in_sizes; (void)n_in; (void)out_size; (void)ws_size;
  const float* x    = (const float*)d_in[0];
  const float* wq   = (const float*)d_in[1];
  const float* wk   = (const float*)d_in[2];
  const float* wv   = (const float*)d_in[3];
  const float* wo   = (const float*)d_in[4];
  const float* cosb = (const float*)d_in[5];
  const float* sinb = (const float*)d_in[6];
  float* out = (float*)d_out;
  char* ws = (char*)d_ws;

  unsigned short* x_bf   = (unsigned short*)(ws);              //  0 ..  8 MB (dead after kexact)
  unsigned short* attn   = (unsigned short*)(ws);              //  0 ..  8 MB (over dead x_bf)
  unsigned short* wT     = (unsigned short*)(ws + 8388608);    //  8 .. 14 MB (wq|wv|wkh)
  unsigned short* woT    = (unsigned short*)(ws + 14680064);   // 14 .. 16 MB
  unsigned short* qv_bf  = (unsigned short*)(ws + 16777216);   // 16 .. 32 MB (dead after rope_pack)
  unsigned short* Opart  = (unsigned short*)(ws + 16777216);   // 16 .. 40 MB (3x8x4096x128 bf16; over dead qv_bf)
  unsigned short* q_bf   = (unsigned short*)(ws + 41943040);   // 40 .. 48 MB
  unsigned short* k_bf   = (unsigned short*)(ws + 50331648);   // 48 .. 56 MB
  unsigned short* vT     = (unsigned short*)(ws + 58720256);   // 56 .. 64 MB
  unsigned short* xm     = (unsigned short*)(ws + 41943040);   // transient, overlaps q_bf
  unsigned short* wkm    = (unsigned short*)(ws + 58720256);   // transient, overlaps vT
  float*          kf32   = (float*)(ws + 67108864);            // 64 .. 80 MB
  float*          xrep   = (float*)(ws + 83886080);            // 80.00 MB
  float*          qrep   = (float*)(ws + 84017152);            // 80.125 MB
  float*          qparts = (float*)(ws + 84148224);            // 80.25 .. 81.25 MB
  float*          scores = (float*)(ws + 85196800);            // 81.25 MB + 32 KB
  float*          mpart  = (float*)(ws + 85229568);            // +384 KB (3x32768 f32)
  float*          lpart  = (float*)(ws + 85622784);            // +384 KB

  unsigned short* wkh = wT + (size_t)2 * 1024 * 1024;

  conv_w<<<dim3(32, 32, 4), 256, 0, stream>>>(wq, wk, wv, wo, wT, woT, wkm);
  conv_x<<<dim3(16384), 256, 0, stream>>>(x, x_bf, xm, xrep);
  gemm_bt<true><<<dim3(16, 32), 256, 0, stream>>>(x_bf, wT, qv_bf, 2048);
  kexact<<<dim3(8, 64), 256, 0, stream>>>(x_bf, xm, wkh, wkm, cosb, sinb, kf32, k_bf);
  qrep_gemm<<<dim3(32, 8), 256, 0, stream>>>(xrep, wq, qparts);
  qsum<<<dim3(128), 256, 0, stream>>>(qparts, qrep);
  rope_pack<<<dim3(64, 8), 256, 0, stream>>>(qv_bf, cosb, sinb, q_bf, vT);
  flash_attn<<<dim3(8, 64, 3), 256, 0, stream>>>(q_bf, k_bf, vT, Opart, mpart, lpart);
  combine<<<dim3(16384), 256, 0, stream>>>(Opart, mpart, lpart, attn);
  gemm_bt64<<<dim3(8, 64), 256, 0, stream>>>(attn, woT, out);
  rep_scores<<<dim3(8, 32), 256, 0, stream>>>(kf32, qrep, cosb, sinb, scores);
  select_topk<<<dim3(1), 256, 0, stream>>>(scores, out + 4194304);
}

// Round 11
// 322.116 us; speedup vs baseline: 1.0408x; 1.0368x over previous
//
#include <hip/hip_runtime.h>
#include <hip/hip_bf16.h>
#include <stdint.h>

#define S_LEN 4096
#define EMB   1024
#define NH    8
#define HD    128

typedef __bf16 bf16x8 __attribute__((ext_vector_type(8)));
typedef float  f32x4  __attribute__((ext_vector_type(4)));
typedef short  s16x4  __attribute__((ext_vector_type(4)));

__device__ __forceinline__ unsigned short f2bf(float f) {
  unsigned int u = __float_as_uint(f);
  u += 0x7fffu + ((u >> 16) & 1u);
  return (unsigned short)(u >> 16);
}
__device__ __forceinline__ float bf2f(unsigned short u) {
  return __uint_as_float(((unsigned int)u) << 16);
}

typedef __attribute__((address_space(3))) void lds_void_t;
typedef const __attribute__((address_space(1))) void gbl_void_t;

__device__ __forceinline__ void load_lds16(const void* g, void* l) {
  __builtin_amdgcn_global_load_lds((gbl_void_t*)g, (lds_void_t*)l, 16, 0, 0);
}

// ---------------- weight transpose+convert ----------------
// wT layout: [0,1M)=wq^T, [1M,2M)=wv^T  (the 2048-wide QV GEMM B);  [2M,3M)=wk^T (kexact)
__global__ __launch_bounds__(256) void conv_w(const float* wq, const float* wk, const float* wv,
                                              const float* wo, unsigned short* wT, unsigned short* woT,
                                              unsigned short* wkm) {
  int z = blockIdx.z;
  const float* src = (z == 0) ? wq : (z == 1) ? wk : (z == 2) ? wv : wo;
  unsigned short* dst = (z == 0) ? wT
                      : (z == 2) ? wT + (size_t)1 * 1024 * 1024
                      : (z == 1) ? wT + (size_t)2 * 1024 * 1024
                                 : woT;
  __shared__ float tl[32][33];
  int tx = threadIdx.x & 31, ty = threadIdx.x >> 5;
  int c0 = blockIdx.x * 32, r0 = blockIdx.y * 32;
#pragma unroll
  for (int i = 0; i < 4; ++i)
    tl[ty + 8 * i][tx] = src[(size_t)(r0 + ty + 8 * i) * 1024 + c0 + tx];
  __syncthreads();
#pragma unroll
  for (int i = 0; i < 4; ++i) {
    float v = tl[tx][ty + 8 * i];
    unsigned short h = f2bf(v);
    size_t o = (size_t)(c0 + ty + 8 * i) * 1024 + r0 + tx;
    dst[o] = h;
    if (z == 1) wkm[o] = f2bf(v - bf2f(h));
  }
}

// ---------------- x convert (2-plane split) + rep-row gather ----------------
__global__ __launch_bounds__(256) void conv_x(const float* x, unsigned short* xh, unsigned short* xm,
                                              float* xrep) {
  int idx = blockIdx.x * 256 + threadIdx.x;
  if (idx < 4194304) {
    float v = x[idx];
    unsigned short h = f2bf(v);
    xh[idx] = h;
    xm[idx] = f2bf(v - bf2f(h));
  }
  if (idx < 32768) {
    int r = idx >> 10, e = idx & 1023;
    xrep[idx] = x[(size_t)(r * 128 + 127) * 1024 + e];
  }
}

// ---------------- bf16 MFMA GEMM: C[M,N] = A[M,K=1024] * B[N,K=1024]^T ----------------
template <bool BF16OUT>
__global__ __launch_bounds__(256) void gemm_bt(const unsigned short* A, const unsigned short* B,
                                               void* Cv, int N) {
  __shared__ unsigned short Asm[4096];
  __shared__ unsigned short Bsm[4096];
  int tid = threadIdx.x;
  int w = tid >> 6, l = tid & 63, quad = l >> 4, l16 = l & 15;
  int wm = w >> 1, wn = w & 1;
  int m0 = blockIdx.y * 128, n0 = blockIdx.x * 128;
  f32x4 acc[4][4];
  f32x4 z4 = {0.f, 0.f, 0.f, 0.f};
#pragma unroll
  for (int i = 0; i < 4; ++i)
#pragma unroll
    for (int j = 0; j < 4; ++j) acc[i][j] = z4;
  const unsigned short* Ag = A + (size_t)m0 * 1024;
  const unsigned short* Bg = B + (size_t)n0 * 1024;
  int sl = (quad ^ ((l16 >> 1) & 3)) * 8;
  for (int kt = 0; kt < 1024; kt += 32) {
#pragma unroll
    for (int it = 0; it < 2; ++it) {
      int c = it * 256 + tid;
      int row = c >> 2, sg = c & 3;
      int sw = (sg ^ ((row >> 1) & 3)) * 8;
      load_lds16(Ag + (size_t)row * 1024 + kt + sw, &Asm[(it * 256 + (tid & 192)) * 8]);
      load_lds16(Bg + (size_t)row * 1024 + kt + sw, &Bsm[(it * 256 + (tid & 192)) * 8]);
    }
    __syncthreads();
    bf16x8 af[4], bfr[4];
#pragma unroll
    for (int i = 0; i < 4; ++i) {
      af[i]  = *(const bf16x8*)&Asm[(wm * 64 + i * 16 + l16) * 32 + sl];
      bfr[i] = *(const bf16x8*)&Bsm[(wn * 64 + i * 16 + l16) * 32 + sl];
    }
#pragma unroll
    for (int mi = 0; mi < 4; ++mi)
#pragma unroll
      for (int ni = 0; ni < 4; ++ni)
        acc[mi][ni] = __builtin_amdgcn_mfma_f32_16x16x32_bf16(af[mi], bfr[ni], acc[mi][ni], 0, 0, 0);
    __syncthreads();
  }
#pragma unroll
  for (int mi = 0; mi < 4; ++mi)
#pragma unroll
    for (int ni = 0; ni < 4; ++ni)
#pragma unroll
      for (int r = 0; r < 4; ++r) {
        int row = m0 + wm * 64 + mi * 16 + quad * 4 + r;
        int col = n0 + wn * 64 + ni * 16 + l16;
        if (BF16OUT)
          ((unsigned short*)Cv)[(size_t)row * N + col] = f2bf(acc[mi][ni][r]);
        else
          ((float*)Cv)[(size_t)row * N + col] = acc[mi][ni][r];
      }
}

// ---------------- 64x128-tile fp32-out GEMM (2 blocks/CU for the out-projection) ----------------
__global__ __launch_bounds__(256) void gemm_bt64(const unsigned short* A, const unsigned short* B,
                                                 float* C) {
  __shared__ unsigned short As[2048];   // 64x32
  __shared__ unsigned short Bs[4096];   // 128x32
  int tid = threadIdx.x;
  int w = tid >> 6, l = tid & 63, quad = l >> 4, l16 = l & 15;
  int wm = w >> 1, wn = w & 1;
  int m0 = blockIdx.y * 64, n0 = blockIdx.x * 128;
  f32x4 acc[2][4];
  f32x4 z4 = {0.f, 0.f, 0.f, 0.f};
#pragma unroll
  for (int i = 0; i < 2; ++i)
#pragma unroll
    for (int j = 0; j < 4; ++j) acc[i][j] = z4;
  const unsigned short* Ag = A + (size_t)m0 * 1024;
  const unsigned short* Bg = B + (size_t)n0 * 1024;
  int arow = tid >> 2, asg = tid & 3;
  int asw = (asg ^ ((arow >> 1) & 3)) * 8;
  int sl = (quad ^ ((l16 >> 1) & 3)) * 8;
  for (int kt = 0; kt < 1024; kt += 32) {
    load_lds16(Ag + (size_t)arow * 1024 + kt + asw, &As[(tid & 192) * 8]);
#pragma unroll
    for (int it = 0; it < 2; ++it) {
      int c = it * 256 + tid;
      int row = c >> 2, sg = c & 3;
      int sw = (sg ^ ((row >> 1) & 3)) * 8;
      load_lds16(Bg + (size_t)row * 1024 + kt + sw, &Bs[(it * 256 + (tid & 192)) * 8]);
    }
    __syncthreads();
    bf16x8 af[2], bfr[4];
#pragma unroll
    for (int i = 0; i < 2; ++i)
      af[i] = *(const bf16x8*)&As[(wm * 32 + i * 16 + l16) * 32 + sl];
#pragma unroll
    for (int j = 0; j < 4; ++j)
      bfr[j] = *(const bf16x8*)&Bs[(wn * 64 + j * 16 + l16) * 32 + sl];
#pragma unroll
    for (int mi = 0; mi < 2; ++mi)
#pragma unroll
      for (int ni = 0; ni < 4; ++ni)
        acc[mi][ni] = __builtin_amdgcn_mfma_f32_16x16x32_bf16(af[mi], bfr[ni], acc[mi][ni], 0, 0, 0);
    __syncthreads();
  }
#pragma unroll
  for (int mi = 0; mi < 2; ++mi)
#pragma unroll
    for (int ni = 0; ni < 4; ++ni)
#pragma unroll
      for (int r = 0; r < 4; ++r) {
        int row = m0 + wm * 32 + mi * 16 + quad * 4 + r;
        int col = n0 + wn * 64 + ni * 16 + l16;
        C[(size_t)row * 1024 + col] = acc[mi][ni][r];
      }
}

// ---------------- exact K-GEMM (2-plane split MFMA, mm-plane dropped) + fused RoPE ----------------
// hh+hm+mh gives ~2^-16 relative accuracy; the mm term (xm*wkm ~ 2^-18 rel) is below fp32
// noise -> dropped (25% fewer MFMAs). Writes roped fp32 K AND bf16 k_bf.
__global__ __launch_bounds__(256) void kexact(const unsigned short* Ah, const unsigned short* Am,
                                              const unsigned short* Bh, const unsigned short* Bm,
                                              const float* cosb, const float* sinb,
                                              float* C, unsigned short* k_bf) {
  __shared__ unsigned short As[2 * 2048];
  __shared__ unsigned short Bs[2 * 4096];
  int tid = threadIdx.x;
  int w = tid >> 6, l = tid & 63, quad = l >> 4, l16 = l & 15;
  int wm = w >> 1, wn = w & 1;
  int m0 = blockIdx.y * 64, n0 = blockIdx.x * 128;
  f32x4 acc[2][4];
  f32x4 z4 = {0.f, 0.f, 0.f, 0.f};
#pragma unroll
  for (int i = 0; i < 2; ++i)
#pragma unroll
    for (int j = 0; j < 4; ++j) acc[i][j] = z4;
  const unsigned short* Aps[2] = {Ah + (size_t)m0 * 1024, Am + (size_t)m0 * 1024};
  const unsigned short* Bps[2] = {Bh + (size_t)n0 * 1024, Bm + (size_t)n0 * 1024};
  int arow = tid >> 2, asg = tid & 3;
  int asw = (asg ^ ((arow >> 1) & 3)) * 8;
  int sl = (quad ^ ((l16 >> 1) & 3)) * 8;
  for (int kt = 0; kt < 1024; kt += 32) {
#pragma unroll
    for (int p = 0; p < 2; ++p) {
      load_lds16(Aps[p] + (size_t)arow * 1024 + kt + asw, &As[p * 2048 + (tid & 192) * 8]);
#pragma unroll
      for (int it = 0; it < 2; ++it) {
        int c = it * 256 + tid;
        int row = c >> 2, sg = c & 3;
        int sw = (sg ^ ((row >> 1) & 3)) * 8;
        load_lds16(Bps[p] + (size_t)row * 1024 + kt + sw,
                   &Bs[p * 4096 + (it * 256 + (tid & 192)) * 8]);
      }
    }
    __syncthreads();
    bf16x8 af[2][2], bfr[2][4];
#pragma unroll
    for (int p = 0; p < 2; ++p) {
#pragma unroll
      for (int i = 0; i < 2; ++i)
        af[p][i] = *(const bf16x8*)&As[p * 2048 + (wm * 32 + i * 16 + l16) * 32 + sl];
#pragma unroll
      for (int j = 0; j < 4; ++j)
        bfr[p][j] = *(const bf16x8*)&Bs[p * 4096 + (wn * 64 + j * 16 + l16) * 32 + sl];
    }
#pragma unroll
    for (int mi = 0; mi < 2; ++mi)
#pragma unroll
      for (int ni = 0; ni < 4; ++ni) {
        f32x4 a = acc[mi][ni];
        a = __builtin_amdgcn_mfma_f32_16x16x32_bf16(af[0][mi], bfr[0][ni], a, 0, 0, 0); // hh
        a = __builtin_amdgcn_mfma_f32_16x16x32_bf16(af[0][mi], bfr[1][ni], a, 0, 0, 0); // hm
        a = __builtin_amdgcn_mfma_f32_16x16x32_bf16(af[1][mi], bfr[0][ni], a, 0, 0, 0); // mh
        // mm (xm*wkm, ~2^-18 rel) dropped: below fp32 noise
        acc[mi][ni] = a;
      }
    __syncthreads();
  }
  // -------- fused RoPE epilogue --------
  float* BsF = (float*)Bs;  // 64x64 fp32 = 16KB b-half exchange
  if (wn == 1) {
#pragma unroll
    for (int mi = 0; mi < 2; ++mi)
#pragma unroll
      for (int ni = 0; ni < 4; ++ni)
#pragma unroll
        for (int r = 0; r < 4; ++r)
          BsF[(wm * 32 + mi * 16 + quad * 4 + r) * 64 + ni * 16 + l16] = acc[mi][ni][r];
  }
  __syncthreads();
  if (wn == 0) {
    int h = blockIdx.x;
#pragma unroll
    for (int mi = 0; mi < 2; ++mi)
#pragma unroll
      for (int ni = 0; ni < 4; ++ni)
#pragma unroll
        for (int r = 0; r < 4; ++r) {
          int rl = wm * 32 + mi * 16 + quad * 4 + r;
          int j  = ni * 16 + l16;
          int s  = m0 + rl;
          float a = acc[mi][ni][r];
          float b = BsF[rl * 64 + j];
          float c = cosb[s * 64 + j], sn = sinb[s * 64 + j];
          float a2 = a * c - b * sn;
          float b2 = b * c + a * sn;
          size_t e = (size_t)s * 1024 + h * 128 + j;
          C[e]      = a2;
          C[e + 64] = b2;
          size_t kb = ((size_t)h * S_LEN + s) * 128 + j;
          k_bf[kb]      = f2bf(a2);
          k_bf[kb + 64] = f2bf(b2);
        }
  }
}

// ---------------- qrep GEMM ----------------
__global__ __launch_bounds__(256) void qrep_gemm(const float* xrep, const float* wq, float* qparts) {
  int n0 = blockIdx.x * 32;
  int p  = blockIdx.y;
  int k0 = p * 128;
  int tid = threadIdx.x;
  __shared__ float xs[32 * 132];
  __shared__ float wsm[128 * 36];
#pragma unroll
  for (int i = 0; i < 4; ++i) {
    int c = tid + 256 * i;
    int m = c >> 5, kc = (c & 31) * 4;
    *(f32x4*)&xs[m * 132 + kc] = *(const f32x4*)&xrep[(size_t)m * 1024 + k0 + kc];
  }
#pragma unroll
  for (int i = 0; i < 4; ++i) {
    int c = tid + 256 * i;
    int k = c >> 3, n = (c & 7) * 4;
    *(f32x4*)&wsm[k * 36 + n] = *(const f32x4*)&wq[(size_t)(k0 + k) * 1024 + n0 + n];
  }
  __syncthreads();
#pragma unroll
  for (int i = 0; i < 4; ++i) {
    int o = tid + 256 * i;
    int m = o >> 5, n = o & 31;
    float acc = 0.f;
#pragma unroll 16
    for (int k = 0; k < 128; ++k) acc += xs[m * 132 + k] * wsm[k * 36 + n];
    qparts[((size_t)p * 32 + m) * 1024 + n0 + n] = acc;
  }
}

__global__ __launch_bounds__(256) void qsum(const float* qparts, float* qrep) {
  int i = blockIdx.x * 256 + threadIdx.x;
  float s = 0.f;
#pragma unroll
  for (int p = 0; p < 8; ++p) s += qparts[(size_t)p * 32768 + i];
  qrep[i] = s;
}

// ---------------- RoPE + pack: q (pre-scaled) + v-transpose from the 2048-wide QV buffer ----------------
__global__ __launch_bounds__(256) void rope_pack(const unsigned short* qv, const float* cosb,
                                                 const float* sinb, unsigned short* q_bf,
                                                 unsigned short* vT) {
  int h = blockIdx.y;
  int s0 = blockIdx.x * 64;
  int tid = threadIdx.x;
  const float sc2 = 0.12751712f;  // (1/sqrt(128)) * log2(e), folded into q
  __shared__ unsigned short vt[128 * 66];
  for (int idx = tid; idx < 4096; idx += 256) {
    int r = idx >> 6, j = idx & 63;
    int s = s0 + r;
    float c = cosb[s * 64 + j], sn = sinb[s * 64 + j];
    const unsigned short* row = qv + (size_t)s * 2048 + h * 128;
    size_t ob = ((size_t)h * S_LEN + s) * 128;
    float a = bf2f(row[j]), b = bf2f(row[j + 64]);
    q_bf[ob + j]      = f2bf((a * c - b * sn) * sc2);
    q_bf[ob + j + 64] = f2bf((b * c + a * sn) * sc2);
  }
  for (int idx = tid; idx < 8192; idx += 256) {
    int r = idx >> 7, d = idx & 127;
    vt[d * 66 + r] = qv[(size_t)(s0 + r) * 2048 + 1024 + h * 128 + d];
  }
  __syncthreads();
  for (int idx = tid; idx < 8192; idx += 256) {
    int d = idx >> 6, c = idx & 63;
    vT[((size_t)h * 128 + d) * S_LEN + s0 + c] = vt[d * 66 + c];
  }
}

// ---------------- flash attention: transposed-S, register P, K-tile 64, 4 blocks/CU ----------------
// R8 configuration (proven best): 2-way key split, counted-vmcnt pipeline.
#define STAGE_K(jj)                                                          \
  {                                                                          \
    _Pragma("unroll")                                                        \
    for (int it = 0; it < 4; ++it) {                                         \
      int c = it * 256 + tid;                                                \
      int kc = c >> 8, cc = c & 255, key = cc >> 2, sg = cc & 3;             \
      int sw = (sg ^ ((key >> 1) & 3)) * 8;                                  \
      load_lds16(kbase + (size_t)((jj) * 64 + key) * 128 + kc * 32 + sw,     \
                 &Ks[(it * 256 + (tid & 192)) * 8]);                         \
    }                                                                        \
  }
#define STAGE_V(jj)                                                          \
  {                                                                          \
    _Pragma("unroll")                                                        \
    for (int it = 0; it < 4; ++it) {                                         \
      int c = it * 256 + tid;                                                \
      int kcv = c >> 9, ccv = c & 511, d = ccv >> 2, sgv = c & 3;            \
      int swv = (sgv ^ ((d >> 1) & 3)) * 8;                                  \
      load_lds16(vbase + (size_t)d * S_LEN + (jj) * 64 + kcv * 32 + swv,     \
                 &Vs[(it * 256 + (tid & 192)) * 8]);                         \
    }                                                                        \
  }

__global__ __launch_bounds__(256, 4) void flash_attn(const unsigned short* q_bf,
                                                     const unsigned short* k_bf,
                                                     const unsigned short* vT,
                                                     unsigned short* Opart,
                                                     float* mpart, float* lpart) {
  int h = blockIdx.x;
  int y = blockIdx.y;
  int qt = (y < 32) ? y : 95 - y;
  int split = blockIdx.z;
  int tid = threadIdx.x, w = tid >> 6, l = tid & 63, quad = l >> 4, l16 = l & 15;
  __shared__ unsigned short Ks[8192]; // 16KB: [kc4(dim)][key64][32dims] swizzled
  __shared__ unsigned short Vs[8192]; // 16KB: [kc2(key)][d128][32keys] swizzled
  const unsigned short* qbase = q_bf + (size_t)h * S_LEN * 128;
  const unsigned short* kbase = k_bf + (size_t)h * S_LEN * 128;
  const unsigned short* vbase = vT + (size_t)h * 128 * S_LEN;
  int sl = (quad ^ ((l16 >> 1) & 3)) * 8;
  int qrow = qt * 64 + w * 16 + l16;
  bf16x8 qf[4];
#pragma unroll
  for (int kc = 0; kc < 4; ++kc)
    qf[kc] = *(const bf16x8*)&qbase[(size_t)qrow * 128 + kc * 32 + quad * 8];
  f32x4 z4 = {0.f, 0.f, 0.f, 0.f};
  f32x4 o[8];
#pragma unroll
  for (int i = 0; i < 8; ++i) o[i] = z4;
  float mrow = -3e38f, lrow = 0.f;
  int ntiles = qt + 1;            // 64-key tiles
  int half0 = (ntiles + 1) >> 1;
  int jlo = split ? half0 : 0;
  int jhi = split ? ntiles : half0;
  if (jlo < jhi) {                // prologue: issue K then V for first tile
    STAGE_K(jlo);
    STAGE_V(jlo);
  }
  for (int j = jlo; j < jhi; ++j) {
    asm volatile("s_waitcnt vmcnt(4)" ::: "memory");
    __builtin_amdgcn_s_barrier();            // all waves: Ks ready
    __builtin_amdgcn_sched_barrier(0);
    f32x4 sa[4];
#pragma unroll
    for (int i = 0; i < 4; ++i) sa[i] = z4;
    __builtin_amdgcn_s_setprio(1);
#pragma unroll
    for (int kc = 0; kc < 4; ++kc) {
#pragma unroll
      for (int ni = 0; ni < 4; ++ni) {
        bf16x8 kf = *(const bf16x8*)&Ks[kc * 2048 + (ni * 16 + l16) * 32 + sl];
        sa[ni] = __builtin_amdgcn_mfma_f32_16x16x32_bf16(kf, qf[kc], sa[ni], 0, 0, 0);
      }
    }
    __builtin_amdgcn_s_setprio(0);
    asm volatile("s_waitcnt vmcnt(0)" ::: "memory");
    __builtin_amdgcn_s_barrier();            // all waves: Vs ready, Ks free
    __builtin_amdgcn_sched_barrier(0);
    if (j + 1 < jhi) STAGE_K(j + 1);         // hides under softmax+PV
    bool diag = (j == qt);
    float vmax = -3e38f;
#pragma unroll
    for (int ni = 0; ni < 4; ++ni)
#pragma unroll
      for (int r = 0; r < 4; ++r) {
        int key = j * 64 + ni * 16 + quad * 4 + r;
        float v = sa[ni][r];
        if (diag && key > qrow) v = -1e10f;
        sa[ni][r] = v;
        vmax = fmaxf(vmax, v);
      }
    vmax = fmaxf(vmax, __shfl_xor(vmax, 16));
    vmax = fmaxf(vmax, __shfl_xor(vmax, 32));
    float mnew = fmaxf(mrow, vmax);
    float alpha = exp2f(mrow - mnew);
    mrow = mnew;
    float rsum = 0.f;
#pragma unroll
    for (int ni = 0; ni < 4; ++ni)
#pragma unroll
      for (int r = 0; r < 4; ++r) {
        float p = exp2f(sa[ni][r] - mnew);
        sa[ni][r] = p;
        rsum += p;
      }
    rsum += __shfl_xor(rsum, 16);
    rsum += __shfl_xor(rsum, 32);
    lrow = lrow * alpha + rsum;
    float ar[4];
#pragma unroll
    for (int r = 0; r < 4; ++r) ar[r] = __shfl(alpha, quad * 4 + r);
#pragma unroll
    for (int nd = 0; nd < 8; ++nd)
#pragma unroll
      for (int r = 0; r < 4; ++r) o[nd][r] *= ar[r];
    __builtin_amdgcn_s_setprio(1);
#pragma unroll
    for (int ni = 0; ni < 4; ++ni) {
      s16x4 pf;
#pragma unroll
      for (int r = 0; r < 4; ++r) {
        __bf16 pb = (__bf16)sa[ni][r];   // native cast -> v_cvt_pk_bf16_f32 (RNE)
        pf[r] = __builtin_bit_cast(short, pb);
      }
      int chunk8 = (ni & 1) * 2 + (quad >> 1);
      int sub = (quad & 1) * 4;
      int kcv = ni >> 1;
#pragma unroll
      for (int nd = 0; nd < 8; ++nd) {
        int d = nd * 16 + l16;
        int slot = chunk8 ^ ((d >> 1) & 3);
        s16x4 vf = *(const s16x4*)&Vs[kcv * 4096 + d * 32 + slot * 8 + sub];
        o[nd] = __builtin_amdgcn_mfma_f32_16x16x16bf16_1k(pf, vf, o[nd], 0, 0, 0);
      }
    }
    __builtin_amdgcn_s_setprio(0);
    __builtin_amdgcn_s_barrier();            // all waves: Vs reads done
    __builtin_amdgcn_sched_barrier(0);
    if (j + 1 < jhi) STAGE_V(j + 1);         // hides under next QK
  }
  float mr[4], lr[4];
#pragma unroll
  for (int r = 0; r < 4; ++r) {
    mr[r] = __shfl(mrow, quad * 4 + r);
    lr[r] = __shfl(lrow, quad * 4 + r);
  }
  size_t pbase = (size_t)(split * 8 + h) * 4096 + qt * 64;
#pragma unroll
  for (int r = 0; r < 4; ++r) {
    int lrw = w * 16 + quad * 4 + r;
#pragma unroll
    for (int nd = 0; nd < 8; ++nd)
      Opart[(pbase + lrw) * 128 + nd * 16 + l16] = f2bf(o[nd][r]);
    if (l16 == 0) {
      mpart[pbase + lrw] = mr[r];
      lpart[pbase + lrw] = lr[r];
    }
  }
}

// ---------------- combine the two key-splits ----------------
__global__ __launch_bounds__(256) void combine(const unsigned short* Opart, const float* mpart,
                                               const float* lpart, unsigned short* attn) {
  int idx = blockIdx.x * 256 + threadIdx.x;  // 8*4096*128
  int h = idx >> 19;
  int rem = idx & 524287;
  int row = rem >> 7, d = rem & 127;
  int r0 = h * 4096 + row;
  int r1 = 32768 + r0;
  float m0 = mpart[r0], m1 = mpart[r1];
  float l0 = lpart[r0], l1 = lpart[r1];
  float m = fmaxf(m0, m1);
  float a0 = exp2f(m0 - m), a1 = exp2f(m1 - m);
  float o0 = bf2f(Opart[(size_t)r0 * 128 + d]);
  float o1 = bf2f(Opart[(size_t)r1 * 128 + d]);
  float denom = a0 * l0 + a1 * l1;
  attn[(size_t)row * 1024 + h * 128 + d] = f2bf((a0 * o0 + a1 * o1) / denom);
}

// ---------------- rep-logit tile scores (XCD-pinned: x = head) ----------------
__global__ __launch_bounds__(256) void rep_scores(const float* krope, const float* qrep,
                                                  const float* cosb, const float* sinb,
                                                  float* scores) {
  int h = blockIdx.x, tt = blockIdx.y;
  int tid = threadIdx.x;
  __shared__ float Kt[128 * 129];
  __shared__ float qv[32 * 128];
  __shared__ float lg[32 * 128];
  for (int idx = tid; idx < 16384; idx += 256) {
    int r = idx >> 7, c = idx & 127;
    Kt[r * 129 + c] = krope[(size_t)(tt * 128 + r) * 1024 + h * 128 + c];
  }
  for (int idx = tid; idx < 2048; idx += 256) {
    int rep = idx >> 6, j = idx & 63;
    int sq = rep * 128 + 127;
    float a = qrep[(size_t)rep * 1024 + h * 128 + j];
    float b = qrep[(size_t)rep * 1024 + h * 128 + j + 64];
    float c = cosb[sq * 64 + j], sn = sinb[sq * 64 + j];
    qv[rep * 128 + j]      = a * c - b * sn;
    qv[rep * 128 + j + 64] = b * c + a * sn;
  }
  __syncthreads();
  int key = tid >> 1, half = tid & 1;
  float kreg[64];
#pragma unroll
  for (int d = 0; d < 64; ++d) kreg[d] = Kt[key * 129 + half * 64 + d];
  for (int rep = 0; rep < 32; ++rep) {
    const float* q = &qv[rep * 128 + half * 64];
    float dot = 0.f;
#pragma unroll
    for (int d = 0; d < 64; ++d) dot += kreg[d] * q[d];
    dot += __shfl_xor(dot, 1);
    if (half == 0) lg[rep * 128 + key] = dot;
  }
  __syncthreads();
  int rep = tid >> 3, chunk = tid & 7;
  float m = -3e38f;
#pragma unroll
  for (int i = 0; i < 16; ++i) m = fmaxf(m, lg[rep * 128 + chunk * 16 + i]);
  m = fmaxf(m, __shfl_xor(m, 1));
  m = fmaxf(m, __shfl_xor(m, 2));
  m = fmaxf(m, __shfl_xor(m, 4));
  if (chunk == 0) scores[((size_t)h * 32 + rep) * 32 + tt] = m;
}

// ---------------- top-8 selection ----------------
__global__ __launch_bounds__(256) void select_topk(const float* scores, float* out_idx) {
  int tid = threadIdx.x;
  int h = tid >> 5, t = tid & 31;
  float vals[32];
#pragma unroll
  for (int tt = 0; tt < 32; ++tt)
    vals[tt] = (tt <= t) ? scores[((size_t)h * 32 + t) * 32 + tt] : -3.0e38f;
  int base = (h * 32 + t) * 8;
  for (int i = 0; i < 8; ++i) {
    float best = -3.4e38f;
    int bi = 0;
#pragma unroll
    for (int c = 0; c < 32; ++c)
      if (vals[c] > best) { best = vals[c]; bi = c; }
    out_idx[base + i] = (float)bi;
    vals[bi] = -3.4e38f;
  }
}

extern "C" void kernel_launch(void* const* d_in, const int* in_sizes, int n_in,
                              void* d_out, int out_size, void* d_ws, size_t ws_size,
                              hipStream_t stream) {
  (void)in_sizes; (void)n_in; (void)out_size; (void)ws_size;
  const float* x    = (const float*)d_in[0];
  const float* wq   = (const float*)d_in[1];
  const float* wk   = (const float*)d_in[2];
  const float* wv   = (const float*)d_in[3];
  const float* wo   = (const float*)d_in[4];
  const float* cosb = (const float*)d_in[5];
  const float* sinb = (const float*)d_in[6];
  float* out = (float*)d_out;
  char* ws = (char*)d_ws;

  unsigned short* x_bf   = (unsigned short*)(ws);              //  0 ..  8 MB (= xh plane)
  unsigned short* wT     = (unsigned short*)(ws + 8388608);    //  8 .. 14 MB (wq|wv|wkh)
  unsigned short* woT    = (unsigned short*)(ws + 14680064);   // 14 .. 16 MB
  unsigned short* qv_bf  = (unsigned short*)(ws + 16777216);   // 16 .. 32 MB (dead after rope_pack)
  unsigned short* attn   = (unsigned short*)(ws + 16777216);   // 16 .. 24 MB
  unsigned short* Opart  = (unsigned short*)(ws + 25165824);   // 24 .. 40 MB (2x8x4096x128 bf16)
  unsigned short* q_bf   = (unsigned short*)(ws + 41943040);   // 40 .. 48 MB
  unsigned short* k_bf   = (unsigned short*)(ws + 50331648);   // 48 .. 56 MB
  unsigned short* vT     = (unsigned short*)(ws + 58720256);   // 56 .. 64 MB
  unsigned short* xm     = (unsigned short*)(ws + 41943040);   // transient, overlaps q_bf
  unsigned short* wkm    = (unsigned short*)(ws + 58720256);   // transient, overlaps vT
  float*          kf32   = (float*)(ws + 67108864);            // 64 .. 80 MB
  float*          xrep   = (float*)(ws + 83886080);            // 80.00 MB
  float*          qrep   = (float*)(ws + 84017152);            // 80.125 MB
  float*          qparts = (float*)(ws + 84148224);            // 80.25 .. 81.25 MB
  float*          scores = (float*)(ws + 85196800);            // 81.25 MB + 32 KB
  float*          mpart  = (float*)(ws + 85229568);            // +256 KB
  float*          lpart  = (float*)(ws + 85491712);            // +256 KB

  unsigned short* wkh = wT + (size_t)2 * 1024 * 1024;

  conv_w<<<dim3(32, 32, 4), 256, 0, stream>>>(wq, wk, wv, wo, wT, woT, wkm);
  conv_x<<<dim3(16384), 256, 0, stream>>>(x, x_bf, xm, xrep);
  gemm_bt<true><<<dim3(16, 32), 256, 0, stream>>>(x_bf, wT, qv_bf, 2048);
  kexact<<<dim3(8, 64), 256, 0, stream>>>(x_bf, xm, wkh, wkm, cosb, sinb, kf32, k_bf);
  qrep_gemm<<<dim3(32, 8), 256, 0, stream>>>(xrep, wq, qparts);
  qsum<<<dim3(128), 256, 0, stream>>>(qparts, qrep);
  rope_pack<<<dim3(64, 8), 256, 0, stream>>>(qv_bf, cosb, sinb, q_bf, vT);
  flash_attn<<<dim3(8, 64, 2), 256, 0, stream>>>(q_bf, k_bf, vT, Opart, mpart, lpart);
  combine<<<dim3(16384), 256, 0, stream>>>(Opart, mpart, lpart, attn);
  gemm_bt64<<<dim3(8, 64), 256, 0, stream>>>(attn, woT, out);
  rep_scores<<<dim3(8, 32), 256, 0, stream>>>(kf32, qrep, cosb, sinb, scores);
  select_topk<<<dim3(1), 256, 0, stream>>>(scores, out + 4194304);
}